// Round 24
// baseline (45.424 us; speedup 1.0000x reference)
//
#include <hip/hip_runtime.h>
#include <hip/hip_bf16.h>
#include <math.h>

#define BB 16
#define CC 64
#define HW 4096
#define MM 1024
#define CK 8
#define CV 32
#define LOG2E 1.4426950408889634f

typedef float f32x4 __attribute__((ext_vector_type(4)));
typedef short s16x8 __attribute__((ext_vector_type(8)));

union U4 { uint4 u; s16x8 s; };

__device__ inline unsigned short bfu(float a) {           // RNE (prep only)
    __hip_bfloat16 h = __float2bfloat16(a);
    union { __hip_bfloat16 h; unsigned short u; } c; c.h = h; return c.u;
}
__device__ inline unsigned int pk2bf(float a, float b) {  // RNE pack
    return (unsigned int)bfu(a) | ((unsigned int)bfu(b) << 16);
}
__device__ inline unsigned int pk2bf_t(float a, float b) { // trunc pack (attn)
    return (__float_as_uint(a) >> 16) | (__float_as_uint(b) & 0xffff0000u);
}

// Hardware exp2 (v_exp_f32, trans pipe).
__device__ inline float hwexp2(float s) {
#if __has_builtin(__builtin_amdgcn_exp2f)
    return __builtin_amdgcn_exp2f(s);
#else
    float r;
    asm volatile("v_exp_f32 %0, %1\n\ts_nop 1" : "=v"(r) : "v"(s));
    return r;
#endif
}
// Pure-VALU exp2 poly (9 single-issue VALU ops).
__device__ inline float fexp2i(float s) {
    float r = rintf(s);
    float f = s - r;
    float p = fmaf(f, 0.00961813f, 0.05550411f);
    p = fmaf(f, p, 0.24022651f);
    p = fmaf(f, p, 0.69314718f);
    p = fmaf(f, p, 1.0f);
    float sc = __int_as_float(((int)r + 127) << 23);
    return p * sc;
}
// MIXED-PIPE exp ledger (direct A/B totals, T=1 structure): no-exp body 17.5us
// (R17 probe); +hwexp2 ~+22us (R18: 46.25 total); +fexp2i ~+28us (R20: 52.4).
// Both pipes are throughput-bound on exp alone -> splitting 4 scores to the
// trans pipe and 4 to VALU per batch runs them CONCURRENTLY: exp cost ->
// ~max(11,14) instead of 22-28.

// Workspace layout (bytes):
//   fxB  bf16 [b][q][8]            @ 0        (1,048,576)
//   gxA  bf16 [b][k][8]            @ 1048576  (262,144)
//   hxC  bf16 [b][ch][k]           @ 1310720  (1,048,576)
//   wvB  bf16 tiled [4][64][8]     @ 2359296  (4,096)
//   frag bf16 [b][g][4][64][8]     @ 2363392  (2,097,152)
#define FXB_OFF 0
#define GXA_OFF 1048576
#define HXC_OFF 1310720
#define WVB_OFF 2359296
#define FRG_OFF 2363392

// ---------------------------------------------------------------------------
// Kernel A: conv f/g/h split by OUTPUT channels (blockIdx.y = chunk:
// 0=f, 1=g, 2..5=h quarters). Pool via shfl_xor(1,2). hxC staged via LDS.
// ---------------------------------------------------------------------------
__global__ __launch_bounds__(256, 6) void prep_kernel(
    const float* __restrict__ x,
    const float* __restrict__ wf, const float* __restrict__ bf,
    const float* __restrict__ wg, const float* __restrict__ bg,
    const float* __restrict__ wh, const float* __restrict__ bh,
    const float* __restrict__ wv,
    unsigned short* __restrict__ fxB, unsigned short* __restrict__ gxA,
    unsigned short* __restrict__ hxC, unsigned short* __restrict__ wvB)
{
    __shared__ __align__(16) float wsm[8 * CC];
    __shared__ __align__(16) unsigned short sHp[64][8];

    int tid   = threadIdx.x;
    int chunk = blockIdx.y;            // 0=f 1=g 2..5=h
    const float* wsrc = (chunk == 0) ? wf : (chunk == 1) ? wg : (wh + (size_t)(chunk - 2) * 8 * CC);
    const float* bsrc = (chunk == 0) ? bf : (chunk == 1) ? bg : (bh + (chunk - 2) * 8);

    for (int i = tid; i < 8 * CC; i += 256) wsm[i] = wsrc[i];

    if (blockIdx.x == 0 && chunk == 0) {
        int t = tid >> 6, ll = tid & 63;
        const float* wr = wv + (size_t)(t * 16 + (ll & 15)) * CV + ((ll >> 4) * 8);
        uint4 wu;
        wu.x = pk2bf(wr[0], wr[1]); wu.y = pk2bf(wr[2], wr[3]);
        wu.z = pk2bf(wr[4], wr[5]); wu.w = pk2bf(wr[6], wr[7]);
        *(uint4*)(wvB + (size_t)tid * 8) = wu;
    }
    __syncthreads();

    int wave = tid >> 6, l = tid & 63;
    int wp = blockIdx.x * 4 + wave;
    int b  = wp >> 6;
    int t2 = wp & 63;
    int rpair = t2 >> 1, chalf = t2 & 1;
    int col = chalf * 32 + (l >> 2) * 2 + (l & 1);
    int row = rpair * 2 + ((l >> 1) & 1);
    int pix = row * 64 + col;

    float o8[8];
#pragma unroll
    for (int o = 0; o < 8; ++o) o8[o] = bsrc[o];

    const float* xp = x + (size_t)b * CC * HW + pix;
#pragma unroll 4
    for (int c4 = 0; c4 < CC; c4 += 4) {
        float v0 = xp[(c4 + 0) * HW];
        float v1 = xp[(c4 + 1) * HW];
        float v2 = xp[(c4 + 2) * HW];
        float v3 = xp[(c4 + 3) * HW];
#pragma unroll
        for (int o = 0; o < 8; ++o) {
            float4 w = *(const float4*)&wsm[o * CC + c4];
            o8[o] = fmaf(w.x, v0, fmaf(w.y, v1, fmaf(w.z, v2, fmaf(w.w, v3, o8[o]))));
        }
    }

    if (chunk == 0) {
        uint4 fu;
        fu.x = pk2bf(o8[0] * LOG2E, o8[1] * LOG2E);
        fu.y = pk2bf(o8[2] * LOG2E, o8[3] * LOG2E);
        fu.z = pk2bf(o8[4] * LOG2E, o8[5] * LOG2E);
        fu.w = pk2bf(o8[6] * LOG2E, o8[7] * LOG2E);
        *(uint4*)(fxB + (size_t)(b * HW + pix) * CK) = fu;
    } else {
#pragma unroll
        for (int o = 0; o < 8; ++o) {
            o8[o] = fmaxf(o8[o], __shfl_xor(o8[o], 1, 64));
            o8[o] = fmaxf(o8[o], __shfl_xor(o8[o], 2, 64));
        }
        int ppl = l >> 2;
        if (chunk == 1) {
            if ((l & 3) == 0) {
                uint4 gu;
                gu.x = pk2bf(o8[0], o8[1]); gu.y = pk2bf(o8[2], o8[3]);
                gu.z = pk2bf(o8[4], o8[5]); gu.w = pk2bf(o8[6], o8[7]);
                *(uint4*)(gxA + (size_t)(b * MM + t2 * 16 + ppl) * CK) = gu;
            }
        } else {
            if ((l & 3) == 0) {
                uint4 hu;
                hu.x = pk2bf(o8[0], o8[1]); hu.y = pk2bf(o8[2], o8[3]);
                hu.z = pk2bf(o8[4], o8[5]); hu.w = pk2bf(o8[6], o8[7]);
                *(uint4*)&sHp[wave * 16 + ppl][0] = hu;
            }
            __syncthreads();
            int ch = tid >> 5, j = tid & 31;
            unsigned int v = (unsigned int)sHp[2 * j][ch]
                           | ((unsigned int)sHp[2 * j + 1][ch] << 16);
            int ppb = (blockIdx.x * 4 & 63) * 16;
            int chg = (chunk - 2) * 8 + ch;
            *(unsigned int*)(hxC + (size_t)(b * CV + chg) * MM + ppb + 2 * j) = v;
        }
    }
}

// ---------------------------------------------------------------------------
// Kernel T: wave-exact operand tiles frag[b][g][4][64][8] (see R10).
// ---------------------------------------------------------------------------
__global__ __launch_bounds__(256) void tile_kernel(
    const unsigned short* __restrict__ gxA, const unsigned short* __restrict__ hxC,
    unsigned short* __restrict__ frag)
{
    int bg = blockIdx.x;
    int b  = bg >> 5, g = bg & 31;
    int tid = threadIdx.x;
    int which = tid >> 6, l = tid & 63;
    int q16 = l & 15, h = l >> 4;
    int prm = ((q16 & 12) << 1) | (q16 & 3);

    const unsigned short* src;
    if (which < 2) {
        src = gxA + (size_t)(b * MM + g * 32 + prm + (which ? 4 : 0)) * CK;
    } else {
        src = hxC + (size_t)(b * CV + prm + ((which == 3) ? 4 : 0)) * MM + g * 32 + h * 8;
    }
    uint4 v = *(const uint4*)src;
    *(uint4*)(frag + ((size_t)bg * 4 + which) * 64 * 8 + (size_t)l * 8) = v;
}

// ---------------------------------------------------------------------------
// Kernel B: MFMA flash attention. Block = 64 queries, 512 thr (8 waves).
// R24 = R23 (T=4, key-eighths) + MIXED-PIPE exp: per 8-score batch, scores
// 0-3 on the trans pipe (v_exp_f32), scores 4-7 on VALU (fexp2i poly) --
// the two pipes issue concurrently instead of one idling. Everything else
// identical to R23 (42.71us). (512,4) = 128-VGPR cap.
// ---------------------------------------------------------------------------
__global__ __launch_bounds__(512, 4) void attn_kernel(
    const float* __restrict__ x,
    const unsigned short* __restrict__ fxB, const unsigned short* __restrict__ frag,
    const unsigned short* __restrict__ wvB,
    const float* __restrict__ bv, const float* __restrict__ gamma,
    float* __restrict__ out)
{
    __shared__ float sAcc[4][8][8][64];   // [qt][kq][elem][lane] 64KB
    __shared__ float sSum[4][8][64];      // 8KB

    int tid = threadIdx.x;
    int l   = tid & 63;
    int w   = tid >> 6;                        // 0..7 = key eighth
    int b   = blockIdx.x >> 6;                 // 64 blocks per batch
    int qb  = (blockIdx.x & 63) * 64;
    int q16 = l & 15;
    int h   = l >> 4;
    bool lo16 = (l < 16);

    U4 qf[4];
#pragma unroll
    for (int t = 0; t < 4; ++t) {
        uint4 v = *(const uint4*)(fxB + (size_t)(b * HW + qb + t * 16 + q16) * CK);
        if (!lo16) { v.x = 0; v.y = 0; v.z = 0; v.w = 0; }
        qf[t].u = v;
    }

    f32x4 zz = {0.f, 0.f, 0.f, 0.f};
    f32x4 acc[4][2];
#pragma unroll
    for (int t = 0; t < 4; ++t) { acc[t][0] = zz; acc[t][1] = zz; }
    float ssum[4] = {0.f, 0.f, 0.f, 0.f};

    const unsigned short* fb = frag + ((size_t)(b * 32 + w * 4) * 4) * 64 * 8
                                    + (size_t)l * 8;

#pragma unroll 2
    for (int gi = 0; gi < 4; ++gi) {
        U4 ga, gb2, v0, v1;
        ga.u  = *(const uint4*)(fb + 0 * 512);
        gb2.u = *(const uint4*)(fb + 1 * 512);
        v0.u  = *(const uint4*)(fb + 2 * 512);
        v1.u  = *(const uint4*)(fb + 3 * 512);
        fb += 2048;

#pragma unroll
        for (int t = 0; t < 4; ++t) {
            f32x4 s0 = __builtin_amdgcn_mfma_f32_16x16x32_bf16(ga.s,  qf[t].s, zz, 0, 0, 0);
            f32x4 s1 = __builtin_amdgcn_mfma_f32_16x16x32_bf16(gb2.s, qf[t].s, zz, 0, 0, 0);
            // mixed-pipe exp: s0 batch on trans pipe, s1 batch on VALU
            float e0 = hwexp2(s0.x), e1 = hwexp2(s0.y), e2 = hwexp2(s0.z), e3 = hwexp2(s0.w);
            float e4 = fexp2i(s1.x), e5 = fexp2i(s1.y), e6 = fexp2i(s1.z), e7 = fexp2i(s1.w);
            ssum[t] += ((e0 + e1) + (e2 + e3)) + ((e4 + e5) + (e6 + e7));
            U4 bp;
            bp.u.x = pk2bf_t(e0, e1); bp.u.y = pk2bf_t(e2, e3);
            bp.u.z = pk2bf_t(e4, e5); bp.u.w = pk2bf_t(e6, e7);
            acc[t][0] = __builtin_amdgcn_mfma_f32_16x16x32_bf16(v0.s, bp.s, acc[t][0], 0, 0, 0);
            acc[t][1] = __builtin_amdgcn_mfma_f32_16x16x32_bf16(v1.s, bp.s, acc[t][1], 0, 0, 0);
        }
    }

#pragma unroll
    for (int t = 0; t < 4; ++t) {
#pragma unroll
        for (int e = 0; e < 4; ++e) {
            sAcc[t][w][e][l]     = acc[t][0][e];
            sAcc[t][w][4 + e][l] = acc[t][1][e];
        }
        sSum[t][w][l] = ssum[t];
    }
    __syncthreads();

    int qt_f = w >> 1;
    int oth  = w & 1;
    f32x4 ca0 = zz, ca1 = zz;
    float cs = 0.f;
#pragma unroll
    for (int k2 = 0; k2 < 8; ++k2) {
#pragma unroll
        for (int e = 0; e < 4; ++e) {
            ca0[e] += sAcc[qt_f][k2][e][l];
            ca1[e] += sAcc[qt_f][k2][4 + e][l];
        }
        cs += sSum[qt_f][k2][l];
    }
    cs += __shfl_xor(cs, 16, 64);
    cs += __shfl_xor(cs, 32, 64);
    float inv = 1.0f / cs;

    U4 mb;
    mb.u.x = pk2bf_t(ca0.x * inv, ca0.y * inv);
    mb.u.y = pk2bf_t(ca0.z * inv, ca0.w * inv);
    mb.u.z = pk2bf_t(ca1.x * inv, ca1.y * inv);
    mb.u.w = pk2bf_t(ca1.z * inv, ca1.w * inv);

    float gm = gamma[0];
    int q = qb + qt_f * 16 + q16;
    const float* xq = x + (size_t)b * CC * HW + q;
    float*       oq = out + (size_t)b * CC * HW + q;
#pragma unroll
    for (int i = 0; i < 2; ++i) {
        int ot = oth * 2 + i;
        U4 wva;
        wva.u = *(const uint4*)(wvB + (size_t)(ot * 64 + l) * CK);
        f32x4 d = __builtin_amdgcn_mfma_f32_16x16x32_bf16(wva.s, mb.s, zz, 0, 0, 0);
#pragma unroll
        for (int r = 0; r < 4; ++r) {
            int o = ot * 16 + h * 4 + r;
            oq[(size_t)o * HW] = xq[(size_t)o * HW] + gm * (d[r] + bv[o]);
        }
    }
}

extern "C" void kernel_launch(void* const* d_in, const int* in_sizes, int n_in,
                              void* d_out, int out_size, void* d_ws, size_t ws_size,
                              hipStream_t stream) {
    const float* x     = (const float*)d_in[0];
    const float* wf    = (const float*)d_in[1];
    const float* bf    = (const float*)d_in[2];
    const float* wg    = (const float*)d_in[3];
    const float* bg    = (const float*)d_in[4];
    const float* wh    = (const float*)d_in[5];
    const float* bh    = (const float*)d_in[6];
    const float* wv    = (const float*)d_in[7];
    const float* bv    = (const float*)d_in[8];
    const float* gamma = (const float*)d_in[9];
    float* out = (float*)d_out;
    char* ws = (char*)d_ws;

    unsigned short* fxB  = (unsigned short*)(ws + FXB_OFF);
    unsigned short* gxA  = (unsigned short*)(ws + GXA_OFF);
    unsigned short* hxC  = (unsigned short*)(ws + HXC_OFF);
    unsigned short* wvB  = (unsigned short*)(ws + WVB_OFF);
    unsigned short* frag = (unsigned short*)(ws + FRG_OFF);

    prep_kernel<<<dim3(256, 6), 256, 0, stream>>>(x, wf, bf, wg, bg, wh, bh, wv,
                                                  fxB, gxA, hxC, wvB);
    tile_kernel<<<512, 256, 0, stream>>>(gxA, hxC, frag);
    attn_kernel<<<1024, 512, 0, stream>>>(x, fxB, frag, wvB, bv, gamma, out);
}

// Round 25
// 39.825 us; speedup vs baseline: 1.1406x; 1.1406x over previous
//
#include <hip/hip_runtime.h>
#include <hip/hip_bf16.h>
#include <math.h>

#define BB 16
#define CC 64
#define HW 4096
#define MM 1024
#define CK 8
#define CV 32
#define LOG2E 1.4426950408889634f

typedef float f32x4 __attribute__((ext_vector_type(4)));
typedef short s16x8 __attribute__((ext_vector_type(8)));

union U4 { uint4 u; s16x8 s; };

__device__ inline unsigned short bfu(float a) {           // RNE (prep only)
    __hip_bfloat16 h = __float2bfloat16(a);
    union { __hip_bfloat16 h; unsigned short u; } c; c.h = h; return c.u;
}
__device__ inline unsigned int pk2bf(float a, float b) {  // RNE pack
    return (unsigned int)bfu(a) | ((unsigned int)bfu(b) << 16);
}
__device__ inline unsigned int pk2bf_t(float a, float b) { // trunc pack (attn)
    return (__float_as_uint(a) >> 16) | (__float_as_uint(b) & 0xffff0000u);
}

// Hardware exp2 (v_exp_f32, trans pipe). A/B ledger (direct totals):
// hwexp2 42.71 (R23) < mixed trans/VALU 45.42 (R24) < fexp2i 52.4 (R20).
// Keep exp ENTIRELY off the VALU pipe -- VALU (pack/ssum/addr) is the
// busier pipe; trans overlaps it.
__device__ inline float hwexp2(float s) {
#if __has_builtin(__builtin_amdgcn_exp2f)
    return __builtin_amdgcn_exp2f(s);
#else
    float r;
    asm volatile("v_exp_f32 %0, %1\n\ts_nop 1" : "=v"(r) : "v"(s));
    return r;
#endif
}

// Workspace layout (bytes):
//   fxB  bf16 [b][q][8]            @ 0        (1,048,576)
//   wvB  bf16 tiled [4][64][8]     @ 2359296  (4,096)
//   frag bf16 [b][g][4][64][8]     @ 2363392  (2,097,152)
// (gxA/hxC intermediates eliminated in R25: prep writes frag directly.)
#define FXB_OFF 0
#define WVB_OFF 2359296
#define FRG_OFF 2363392

// ---------------------------------------------------------------------------
// Kernel A: conv f/g/h split by OUTPUT channels (blockIdx.y = chunk:
// 0=f, 1=g, 2..5=h quarters). Pool via shfl_xor(1,2).
// R25: writes frag operand tiles DIRECTLY (tile_kernel eliminated):
//  - chunk 1: each pooled-px g-record goes to its 4 h-replicated frag slots
//    via the inverse perm  q16=(r&3)|((r>>1)&12), which=(r>>2)&1, r=pp&31.
//  - chunks 2-5: block's sHp tile [64 px][8 ch] holds exactly the data for
//    64 V-records (8 ch x 2 g-groups x 4 h); 64 threads emit one each.
// ---------------------------------------------------------------------------
__global__ __launch_bounds__(256, 6) void prep_kernel(
    const float* __restrict__ x,
    const float* __restrict__ wf, const float* __restrict__ bf,
    const float* __restrict__ wg, const float* __restrict__ bg,
    const float* __restrict__ wh, const float* __restrict__ bh,
    const float* __restrict__ wv,
    unsigned short* __restrict__ fxB, unsigned short* __restrict__ wvB,
    unsigned short* __restrict__ frag)
{
    __shared__ __align__(16) float wsm[8 * CC];
    __shared__ __align__(16) unsigned short sHp[64][8];

    int tid   = threadIdx.x;
    int chunk = blockIdx.y;            // 0=f 1=g 2..5=h
    const float* wsrc = (chunk == 0) ? wf : (chunk == 1) ? wg : (wh + (size_t)(chunk - 2) * 8 * CC);
    const float* bsrc = (chunk == 0) ? bf : (chunk == 1) ? bg : (bh + (chunk - 2) * 8);

    for (int i = tid; i < 8 * CC; i += 256) wsm[i] = wsrc[i];

    if (blockIdx.x == 0 && chunk == 0) {
        int t = tid >> 6, ll = tid & 63;
        const float* wr = wv + (size_t)(t * 16 + (ll & 15)) * CV + ((ll >> 4) * 8);
        uint4 wu;
        wu.x = pk2bf(wr[0], wr[1]); wu.y = pk2bf(wr[2], wr[3]);
        wu.z = pk2bf(wr[4], wr[5]); wu.w = pk2bf(wr[6], wr[7]);
        *(uint4*)(wvB + (size_t)tid * 8) = wu;
    }
    __syncthreads();

    int wave = tid >> 6, l = tid & 63;
    int wp = blockIdx.x * 4 + wave;    // wave-position 0..1023
    int b  = wp >> 6;                  // batch (same for whole block: 4|64)
    int t2 = wp & 63;
    int rpair = t2 >> 1, chalf = t2 & 1;
    int col = chalf * 32 + (l >> 2) * 2 + (l & 1);
    int row = rpair * 2 + ((l >> 1) & 1);
    int pix = row * 64 + col;

    float o8[8];
#pragma unroll
    for (int o = 0; o < 8; ++o) o8[o] = bsrc[o];

    const float* xp = x + (size_t)b * CC * HW + pix;
#pragma unroll 4
    for (int c4 = 0; c4 < CC; c4 += 4) {
        float v0 = xp[(c4 + 0) * HW];
        float v1 = xp[(c4 + 1) * HW];
        float v2 = xp[(c4 + 2) * HW];
        float v3 = xp[(c4 + 3) * HW];
#pragma unroll
        for (int o = 0; o < 8; ++o) {
            float4 w = *(const float4*)&wsm[o * CC + c4];
            o8[o] = fmaf(w.x, v0, fmaf(w.y, v1, fmaf(w.z, v2, fmaf(w.w, v3, o8[o]))));
        }
    }

    if (chunk == 0) {
        // f(x): *log2e, bf16, full-res
        uint4 fu;
        fu.x = pk2bf(o8[0] * LOG2E, o8[1] * LOG2E);
        fu.y = pk2bf(o8[2] * LOG2E, o8[3] * LOG2E);
        fu.z = pk2bf(o8[4] * LOG2E, o8[5] * LOG2E);
        fu.w = pk2bf(o8[6] * LOG2E, o8[7] * LOG2E);
        *(uint4*)(fxB + (size_t)(b * HW + pix) * CK) = fu;
    } else {
        // 2x2 maxpool
#pragma unroll
        for (int o = 0; o < 8; ++o) {
            o8[o] = fmaxf(o8[o], __shfl_xor(o8[o], 1, 64));
            o8[o] = fmaxf(o8[o], __shfl_xor(o8[o], 2, 64));
        }
        int ppl = l >> 2;                          // pooled index in wave, 0..15
        if (chunk == 1) {
            if ((l & 3) == 0) {
                uint4 gu;
                gu.x = pk2bf(o8[0], o8[1]); gu.y = pk2bf(o8[2], o8[3]);
                gu.z = pk2bf(o8[4], o8[5]); gu.w = pk2bf(o8[6], o8[7]);
                // direct frag QK-record write (4 h-replicated slots)
                int pp = rpair * 32 + chalf * 16 + ppl;   // pooled px in batch
                int r  = pp & 31, g = pp >> 5;
                int q16d  = (r & 3) | ((r >> 1) & 12);    // inverse perm
                int which = (r >> 2) & 1;
                size_t base = (size_t)((b * 32 + g) * 4 + which) * 64 * 8;
#pragma unroll
                for (int hh = 0; hh < 4; ++hh)
                    *(uint4*)(frag + base + (size_t)(hh * 16 + q16d) * 8) = gu;
            }
        } else {
            if ((l & 3) == 0) {
                uint4 hu;
                hu.x = pk2bf(o8[0], o8[1]); hu.y = pk2bf(o8[2], o8[3]);
                hu.z = pk2bf(o8[4], o8[5]); hu.w = pk2bf(o8[6], o8[7]);
                *(uint4*)&sHp[wave * 16 + ppl][0] = hu;
            }
            __syncthreads();
            // direct frag V-record build: 64 records (8 ch x 2 g x 4 h)
            if (tid < 64) {
                int cl = tid & 7, gg = (tid >> 3) & 1, hh = tid >> 4;
                int c  = (chunk - 2) * 8 + cl;            // global channel
                int which = ((c >> 2) & 1) ? 3 : 2;
                int prm   = (which == 3) ? (c - 4) : c;
                int q16d  = (prm & 3) | ((prm >> 1) & 12);
                int ppb   = (blockIdx.x * 4 & 63) * 16;   // block's pooled base
                int g     = (ppb >> 5) + gg;
                int px    = gg * 32 + hh * 8;
                uint4 hv;
                hv.x = (unsigned)sHp[px + 0][cl] | ((unsigned)sHp[px + 1][cl] << 16);
                hv.y = (unsigned)sHp[px + 2][cl] | ((unsigned)sHp[px + 3][cl] << 16);
                hv.z = (unsigned)sHp[px + 4][cl] | ((unsigned)sHp[px + 5][cl] << 16);
                hv.w = (unsigned)sHp[px + 6][cl] | ((unsigned)sHp[px + 7][cl] << 16);
                *(uint4*)(frag + ((size_t)((b * 32 + g) * 4 + which) * 64
                                  + hh * 16 + q16d) * 8) = hv;
            }
        }
    }
}

// ---------------------------------------------------------------------------
// Kernel B: MFMA flash attention. Block = 64 queries, 512 thr (8 waves).
// R23's exact kernel (best: 42.71us total): T=4 Q-tiles per wave over its
// key-EIGHTH (kq=w, 128 keys = 4 frag groups); pure hwexp2 (trans pipe);
// (512,4) = 128-VGPR cap. Combine: 2 waves/qt, 2 ot each.
// ---------------------------------------------------------------------------
__global__ __launch_bounds__(512, 4) void attn_kernel(
    const float* __restrict__ x,
    const unsigned short* __restrict__ fxB, const unsigned short* __restrict__ frag,
    const unsigned short* __restrict__ wvB,
    const float* __restrict__ bv, const float* __restrict__ gamma,
    float* __restrict__ out)
{
    __shared__ float sAcc[4][8][8][64];   // [qt][kq][elem][lane] 64KB
    __shared__ float sSum[4][8][64];      // 8KB

    int tid = threadIdx.x;
    int l   = tid & 63;
    int w   = tid >> 6;                        // 0..7 = key eighth
    int b   = blockIdx.x >> 6;                 // 64 blocks per batch
    int qb  = (blockIdx.x & 63) * 64;
    int q16 = l & 15;
    int h   = l >> 4;
    bool lo16 = (l < 16);

    U4 qf[4];
#pragma unroll
    for (int t = 0; t < 4; ++t) {
        uint4 v = *(const uint4*)(fxB + (size_t)(b * HW + qb + t * 16 + q16) * CK);
        if (!lo16) { v.x = 0; v.y = 0; v.z = 0; v.w = 0; }
        qf[t].u = v;
    }

    f32x4 zz = {0.f, 0.f, 0.f, 0.f};
    f32x4 acc[4][2];
#pragma unroll
    for (int t = 0; t < 4; ++t) { acc[t][0] = zz; acc[t][1] = zz; }
    float ssum[4] = {0.f, 0.f, 0.f, 0.f};

    const unsigned short* fb = frag + ((size_t)(b * 32 + w * 4) * 4) * 64 * 8
                                    + (size_t)l * 8;

#pragma unroll 2
    for (int gi = 0; gi < 4; ++gi) {
        U4 ga, gb2, v0, v1;
        ga.u  = *(const uint4*)(fb + 0 * 512);
        gb2.u = *(const uint4*)(fb + 1 * 512);
        v0.u  = *(const uint4*)(fb + 2 * 512);
        v1.u  = *(const uint4*)(fb + 3 * 512);
        fb += 2048;

#pragma unroll
        for (int t = 0; t < 4; ++t) {
            f32x4 s0 = __builtin_amdgcn_mfma_f32_16x16x32_bf16(ga.s,  qf[t].s, zz, 0, 0, 0);
            f32x4 s1 = __builtin_amdgcn_mfma_f32_16x16x32_bf16(gb2.s, qf[t].s, zz, 0, 0, 0);
            float e0 = hwexp2(s0.x), e1 = hwexp2(s0.y), e2 = hwexp2(s0.z), e3 = hwexp2(s0.w);
            float e4 = hwexp2(s1.x), e5 = hwexp2(s1.y), e6 = hwexp2(s1.z), e7 = hwexp2(s1.w);
            ssum[t] += ((e0 + e1) + (e2 + e3)) + ((e4 + e5) + (e6 + e7));
            U4 bp;
            bp.u.x = pk2bf_t(e0, e1); bp.u.y = pk2bf_t(e2, e3);
            bp.u.z = pk2bf_t(e4, e5); bp.u.w = pk2bf_t(e6, e7);
            acc[t][0] = __builtin_amdgcn_mfma_f32_16x16x32_bf16(v0.s, bp.s, acc[t][0], 0, 0, 0);
            acc[t][1] = __builtin_amdgcn_mfma_f32_16x16x32_bf16(v1.s, bp.s, acc[t][1], 0, 0, 0);
        }
    }

#pragma unroll
    for (int t = 0; t < 4; ++t) {
#pragma unroll
        for (int e = 0; e < 4; ++e) {
            sAcc[t][w][e][l]     = acc[t][0][e];
            sAcc[t][w][4 + e][l] = acc[t][1][e];
        }
        sSum[t][w][l] = ssum[t];
    }
    __syncthreads();

    int qt_f = w >> 1;
    int oth  = w & 1;
    f32x4 ca0 = zz, ca1 = zz;
    float cs = 0.f;
#pragma unroll
    for (int k2 = 0; k2 < 8; ++k2) {
#pragma unroll
        for (int e = 0; e < 4; ++e) {
            ca0[e] += sAcc[qt_f][k2][e][l];
            ca1[e] += sAcc[qt_f][k2][4 + e][l];
        }
        cs += sSum[qt_f][k2][l];
    }
    cs += __shfl_xor(cs, 16, 64);
    cs += __shfl_xor(cs, 32, 64);
    float inv = 1.0f / cs;

    U4 mb;
    mb.u.x = pk2bf_t(ca0.x * inv, ca0.y * inv);
    mb.u.y = pk2bf_t(ca0.z * inv, ca0.w * inv);
    mb.u.z = pk2bf_t(ca1.x * inv, ca1.y * inv);
    mb.u.w = pk2bf_t(ca1.z * inv, ca1.w * inv);

    float gm = gamma[0];
    int q = qb + qt_f * 16 + q16;
    const float* xq = x + (size_t)b * CC * HW + q;
    float*       oq = out + (size_t)b * CC * HW + q;
#pragma unroll
    for (int i = 0; i < 2; ++i) {
        int ot = oth * 2 + i;
        U4 wva;
        wva.u = *(const uint4*)(wvB + (size_t)(ot * 64 + l) * CK);
        f32x4 d = __builtin_amdgcn_mfma_f32_16x16x32_bf16(wva.s, mb.s, zz, 0, 0, 0);
#pragma unroll
        for (int r = 0; r < 4; ++r) {
            int o = ot * 16 + h * 4 + r;
            oq[(size_t)o * HW] = xq[(size_t)o * HW] + gm * (d[r] + bv[o]);
        }
    }
}

extern "C" void kernel_launch(void* const* d_in, const int* in_sizes, int n_in,
                              void* d_out, int out_size, void* d_ws, size_t ws_size,
                              hipStream_t stream) {
    const float* x     = (const float*)d_in[0];
    const float* wf    = (const float*)d_in[1];
    const float* bf    = (const float*)d_in[2];
    const float* wg    = (const float*)d_in[3];
    const float* bg    = (const float*)d_in[4];
    const float* wh    = (const float*)d_in[5];
    const float* bh    = (const float*)d_in[6];
    const float* wv    = (const float*)d_in[7];
    const float* bv    = (const float*)d_in[8];
    const float* gamma = (const float*)d_in[9];
    float* out = (float*)d_out;
    char* ws = (char*)d_ws;

    unsigned short* fxB  = (unsigned short*)(ws + FXB_OFF);
    unsigned short* wvB  = (unsigned short*)(ws + WVB_OFF);
    unsigned short* frag = (unsigned short*)(ws + FRG_OFF);

    // Kernel A: conv + pool + DIRECT frag-tile emission (tile_kernel gone)
    prep_kernel<<<dim3(256, 6), 256, 0, stream>>>(x, wf, bf, wg, bg, wh, bh, wv,
                                                  fxB, wvB, frag);
    // Kernel B: 1024 blocks x 512 thr; 64 q/block, T=4 Q-tiles x key-eighths
    attn_kernel<<<1024, 512, 0, stream>>>(x, fxB, frag, wvB, bv, gamma, out);
}

// Round 26
// 39.173 us; speedup vs baseline: 1.1596x; 1.0166x over previous
//
#include <hip/hip_runtime.h>
#include <hip/hip_bf16.h>
#include <math.h>

#define BB 16
#define CC 64
#define HW 4096
#define MM 1024
#define CK 8
#define CV 32
#define LOG2E 1.4426950408889634f

typedef float f32x4 __attribute__((ext_vector_type(4)));
typedef short s16x8 __attribute__((ext_vector_type(8)));

union U4 { uint4 u; s16x8 s; };

__device__ inline unsigned short bfu(float a) {           // RNE (prep only)
    __hip_bfloat16 h = __float2bfloat16(a);
    union { __hip_bfloat16 h; unsigned short u; } c; c.h = h; return c.u;
}
__device__ inline unsigned int pk2bf(float a, float b) {  // RNE pack
    return (unsigned int)bfu(a) | ((unsigned int)bfu(b) << 16);
}
__device__ inline unsigned int pk2bf_t(float a, float b) { // trunc pack (attn)
    return (__float_as_uint(a) >> 16) | (__float_as_uint(b) & 0xffff0000u);
}

// Hardware exp2 (v_exp_f32, trans pipe). A/B ledger (direct totals):
// hwexp2 42.71 (R23) < mixed trans/VALU 45.42 (R24) < fexp2i 52.4 (R20).
// Keep exp ENTIRELY off the VALU pipe.
__device__ inline float hwexp2(float s) {
#if __has_builtin(__builtin_amdgcn_exp2f)
    return __builtin_amdgcn_exp2f(s);
#else
    float r;
    asm volatile("v_exp_f32 %0, %1\n\ts_nop 1" : "=v"(r) : "v"(s));
    return r;
#endif
}

// Workspace layout (bytes):
//   fxB  bf16 [b][q][8]            @ 0        (1,048,576)
//   wvB  bf16 tiled [4][64][8]     @ 2359296  (4,096)
//   frag bf16 [b][g][4][64][8]     @ 2363392  (2,097,152)
#define FXB_OFF 0
#define WVB_OFF 2359296
#define FRG_OFF 2363392

// ---------------------------------------------------------------------------
// Kernel A: conv f/g/h split by OUTPUT channels (blockIdx.y = chunk:
// 0=f, 1=g, 2..5=h quarters). Pool via shfl_xor(1,2). Writes frag operand
// tiles DIRECTLY (no tile_kernel): chunk 1 scatters each g-record to its 4
// h-replicated slots via inverse perm; chunks 2-5 emit 64 V-records from
// the block's sHp tile.
// ---------------------------------------------------------------------------
__global__ __launch_bounds__(256, 6) void prep_kernel(
    const float* __restrict__ x,
    const float* __restrict__ wf, const float* __restrict__ bf,
    const float* __restrict__ wg, const float* __restrict__ bg,
    const float* __restrict__ wh, const float* __restrict__ bh,
    const float* __restrict__ wv,
    unsigned short* __restrict__ fxB, unsigned short* __restrict__ wvB,
    unsigned short* __restrict__ frag)
{
    __shared__ __align__(16) float wsm[8 * CC];
    __shared__ __align__(16) unsigned short sHp[64][8];

    int tid   = threadIdx.x;
    int chunk = blockIdx.y;            // 0=f 1=g 2..5=h
    const float* wsrc = (chunk == 0) ? wf : (chunk == 1) ? wg : (wh + (size_t)(chunk - 2) * 8 * CC);
    const float* bsrc = (chunk == 0) ? bf : (chunk == 1) ? bg : (bh + (chunk - 2) * 8);

    for (int i = tid; i < 8 * CC; i += 256) wsm[i] = wsrc[i];

    if (blockIdx.x == 0 && chunk == 0) {
        int t = tid >> 6, ll = tid & 63;
        const float* wr = wv + (size_t)(t * 16 + (ll & 15)) * CV + ((ll >> 4) * 8);
        uint4 wu;
        wu.x = pk2bf(wr[0], wr[1]); wu.y = pk2bf(wr[2], wr[3]);
        wu.z = pk2bf(wr[4], wr[5]); wu.w = pk2bf(wr[6], wr[7]);
        *(uint4*)(wvB + (size_t)tid * 8) = wu;
    }
    __syncthreads();

    int wave = tid >> 6, l = tid & 63;
    int wp = blockIdx.x * 4 + wave;    // wave-position 0..1023
    int b  = wp >> 6;                  // batch (same for whole block: 4|64)
    int t2 = wp & 63;
    int rpair = t2 >> 1, chalf = t2 & 1;
    int col = chalf * 32 + (l >> 2) * 2 + (l & 1);
    int row = rpair * 2 + ((l >> 1) & 1);
    int pix = row * 64 + col;

    float o8[8];
#pragma unroll
    for (int o = 0; o < 8; ++o) o8[o] = bsrc[o];

    const float* xp = x + (size_t)b * CC * HW + pix;
#pragma unroll 4
    for (int c4 = 0; c4 < CC; c4 += 4) {
        float v0 = xp[(c4 + 0) * HW];
        float v1 = xp[(c4 + 1) * HW];
        float v2 = xp[(c4 + 2) * HW];
        float v3 = xp[(c4 + 3) * HW];
#pragma unroll
        for (int o = 0; o < 8; ++o) {
            float4 w = *(const float4*)&wsm[o * CC + c4];
            o8[o] = fmaf(w.x, v0, fmaf(w.y, v1, fmaf(w.z, v2, fmaf(w.w, v3, o8[o]))));
        }
    }

    if (chunk == 0) {
        uint4 fu;
        fu.x = pk2bf(o8[0] * LOG2E, o8[1] * LOG2E);
        fu.y = pk2bf(o8[2] * LOG2E, o8[3] * LOG2E);
        fu.z = pk2bf(o8[4] * LOG2E, o8[5] * LOG2E);
        fu.w = pk2bf(o8[6] * LOG2E, o8[7] * LOG2E);
        *(uint4*)(fxB + (size_t)(b * HW + pix) * CK) = fu;
    } else {
#pragma unroll
        for (int o = 0; o < 8; ++o) {
            o8[o] = fmaxf(o8[o], __shfl_xor(o8[o], 1, 64));
            o8[o] = fmaxf(o8[o], __shfl_xor(o8[o], 2, 64));
        }
        int ppl = l >> 2;
        if (chunk == 1) {
            if ((l & 3) == 0) {
                uint4 gu;
                gu.x = pk2bf(o8[0], o8[1]); gu.y = pk2bf(o8[2], o8[3]);
                gu.z = pk2bf(o8[4], o8[5]); gu.w = pk2bf(o8[6], o8[7]);
                int pp = rpair * 32 + chalf * 16 + ppl;
                int r  = pp & 31, g = pp >> 5;
                int q16d  = (r & 3) | ((r >> 1) & 12);
                int which = (r >> 2) & 1;
                size_t base = (size_t)((b * 32 + g) * 4 + which) * 64 * 8;
#pragma unroll
                for (int hh = 0; hh < 4; ++hh)
                    *(uint4*)(frag + base + (size_t)(hh * 16 + q16d) * 8) = gu;
            }
        } else {
            if ((l & 3) == 0) {
                uint4 hu;
                hu.x = pk2bf(o8[0], o8[1]); hu.y = pk2bf(o8[2], o8[3]);
                hu.z = pk2bf(o8[4], o8[5]); hu.w = pk2bf(o8[6], o8[7]);
                *(uint4*)&sHp[wave * 16 + ppl][0] = hu;
            }
            __syncthreads();
            if (tid < 64) {
                int cl = tid & 7, gg = (tid >> 3) & 1, hh = tid >> 4;
                int c  = (chunk - 2) * 8 + cl;
                int which = ((c >> 2) & 1) ? 3 : 2;
                int prm   = (which == 3) ? (c - 4) : c;
                int q16d  = (prm & 3) | ((prm >> 1) & 12);
                int ppb   = (blockIdx.x * 4 & 63) * 16;
                int g     = (ppb >> 5) + gg;
                int px    = gg * 32 + hh * 8;
                uint4 hv;
                hv.x = (unsigned)sHp[px + 0][cl] | ((unsigned)sHp[px + 1][cl] << 16);
                hv.y = (unsigned)sHp[px + 2][cl] | ((unsigned)sHp[px + 3][cl] << 16);
                hv.z = (unsigned)sHp[px + 4][cl] | ((unsigned)sHp[px + 5][cl] << 16);
                hv.w = (unsigned)sHp[px + 6][cl] | ((unsigned)sHp[px + 7][cl] << 16);
                *(uint4*)(frag + ((size_t)((b * 32 + g) * 4 + which) * 64
                                  + hh * 16 + q16d) * 8) = hv;
            }
        }
    }
}

// ---------------------------------------------------------------------------
// Kernel B: MFMA flash attention. Block = 64 queries, 512 thr (8 waves).
// R26 = R25 (best: 39.83us) + s_setprio(1/0) bracketing the per-group
// MFMA+exp cluster (guide T5: +4-7% on attn when waves have phase
// diversity -- our main loop is barrier-free so waves drift). Everything
// else byte-identical. (512,4) = 128-VGPR cap.
// ---------------------------------------------------------------------------
__global__ __launch_bounds__(512, 4) void attn_kernel(
    const float* __restrict__ x,
    const unsigned short* __restrict__ fxB, const unsigned short* __restrict__ frag,
    const unsigned short* __restrict__ wvB,
    const float* __restrict__ bv, const float* __restrict__ gamma,
    float* __restrict__ out)
{
    __shared__ float sAcc[4][8][8][64];   // [qt][kq][elem][lane] 64KB
    __shared__ float sSum[4][8][64];      // 8KB

    int tid = threadIdx.x;
    int l   = tid & 63;
    int w   = tid >> 6;                        // 0..7 = key eighth
    int b   = blockIdx.x >> 6;                 // 64 blocks per batch
    int qb  = (blockIdx.x & 63) * 64;
    int q16 = l & 15;
    int h   = l >> 4;
    bool lo16 = (l < 16);

    U4 qf[4];
#pragma unroll
    for (int t = 0; t < 4; ++t) {
        uint4 v = *(const uint4*)(fxB + (size_t)(b * HW + qb + t * 16 + q16) * CK);
        if (!lo16) { v.x = 0; v.y = 0; v.z = 0; v.w = 0; }
        qf[t].u = v;
    }

    f32x4 zz = {0.f, 0.f, 0.f, 0.f};
    f32x4 acc[4][2];
#pragma unroll
    for (int t = 0; t < 4; ++t) { acc[t][0] = zz; acc[t][1] = zz; }
    float ssum[4] = {0.f, 0.f, 0.f, 0.f};

    const unsigned short* fb = frag + ((size_t)(b * 32 + w * 4) * 4) * 64 * 8
                                    + (size_t)l * 8;

#pragma unroll 2
    for (int gi = 0; gi < 4; ++gi) {
        U4 ga, gb2, v0, v1;
        ga.u  = *(const uint4*)(fb + 0 * 512);
        gb2.u = *(const uint4*)(fb + 1 * 512);
        v0.u  = *(const uint4*)(fb + 2 * 512);
        v1.u  = *(const uint4*)(fb + 3 * 512);
        fb += 2048;

        __builtin_amdgcn_s_setprio(1);     // favor this wave through the
                                           // MFMA+exp cluster (T5)
#pragma unroll
        for (int t = 0; t < 4; ++t) {
            f32x4 s0 = __builtin_amdgcn_mfma_f32_16x16x32_bf16(ga.s,  qf[t].s, zz, 0, 0, 0);
            f32x4 s1 = __builtin_amdgcn_mfma_f32_16x16x32_bf16(gb2.s, qf[t].s, zz, 0, 0, 0);
            float e0 = hwexp2(s0.x), e1 = hwexp2(s0.y), e2 = hwexp2(s0.z), e3 = hwexp2(s0.w);
            float e4 = hwexp2(s1.x), e5 = hwexp2(s1.y), e6 = hwexp2(s1.z), e7 = hwexp2(s1.w);
            ssum[t] += ((e0 + e1) + (e2 + e3)) + ((e4 + e5) + (e6 + e7));
            U4 bp;
            bp.u.x = pk2bf_t(e0, e1); bp.u.y = pk2bf_t(e2, e3);
            bp.u.z = pk2bf_t(e4, e5); bp.u.w = pk2bf_t(e6, e7);
            acc[t][0] = __builtin_amdgcn_mfma_f32_16x16x32_bf16(v0.s, bp.s, acc[t][0], 0, 0, 0);
            acc[t][1] = __builtin_amdgcn_mfma_f32_16x16x32_bf16(v1.s, bp.s, acc[t][1], 0, 0, 0);
        }
        __builtin_amdgcn_s_setprio(0);
    }

#pragma unroll
    for (int t = 0; t < 4; ++t) {
#pragma unroll
        for (int e = 0; e < 4; ++e) {
            sAcc[t][w][e][l]     = acc[t][0][e];
            sAcc[t][w][4 + e][l] = acc[t][1][e];
        }
        sSum[t][w][l] = ssum[t];
    }
    __syncthreads();

    int qt_f = w >> 1;
    int oth  = w & 1;
    f32x4 ca0 = zz, ca1 = zz;
    float cs = 0.f;
#pragma unroll
    for (int k2 = 0; k2 < 8; ++k2) {
#pragma unroll
        for (int e = 0; e < 4; ++e) {
            ca0[e] += sAcc[qt_f][k2][e][l];
            ca1[e] += sAcc[qt_f][k2][4 + e][l];
        }
        cs += sSum[qt_f][k2][l];
    }
    cs += __shfl_xor(cs, 16, 64);
    cs += __shfl_xor(cs, 32, 64);
    float inv = 1.0f / cs;

    U4 mb;
    mb.u.x = pk2bf_t(ca0.x * inv, ca0.y * inv);
    mb.u.y = pk2bf_t(ca0.z * inv, ca0.w * inv);
    mb.u.z = pk2bf_t(ca1.x * inv, ca1.y * inv);
    mb.u.w = pk2bf_t(ca1.z * inv, ca1.w * inv);

    float gm = gamma[0];
    int q = qb + qt_f * 16 + q16;
    const float* xq = x + (size_t)b * CC * HW + q;
    float*       oq = out + (size_t)b * CC * HW + q;
#pragma unroll
    for (int i = 0; i < 2; ++i) {
        int ot = oth * 2 + i;
        U4 wva;
        wva.u = *(const uint4*)(wvB + (size_t)(ot * 64 + l) * CK);
        f32x4 d = __builtin_amdgcn_mfma_f32_16x16x32_bf16(wva.s, mb.s, zz, 0, 0, 0);
#pragma unroll
        for (int r = 0; r < 4; ++r) {
            int o = ot * 16 + h * 4 + r;
            oq[(size_t)o * HW] = xq[(size_t)o * HW] + gm * (d[r] + bv[o]);
        }
    }
}

extern "C" void kernel_launch(void* const* d_in, const int* in_sizes, int n_in,
                              void* d_out, int out_size, void* d_ws, size_t ws_size,
                              hipStream_t stream) {
    const float* x     = (const float*)d_in[0];
    const float* wf    = (const float*)d_in[1];
    const float* bf    = (const float*)d_in[2];
    const float* wg    = (const float*)d_in[3];
    const float* bg    = (const float*)d_in[4];
    const float* wh    = (const float*)d_in[5];
    const float* bh    = (const float*)d_in[6];
    const float* wv    = (const float*)d_in[7];
    const float* bv    = (const float*)d_in[8];
    const float* gamma = (const float*)d_in[9];
    float* out = (float*)d_out;
    char* ws = (char*)d_ws;

    unsigned short* fxB  = (unsigned short*)(ws + FXB_OFF);
    unsigned short* wvB  = (unsigned short*)(ws + WVB_OFF);
    unsigned short* frag = (unsigned short*)(ws + FRG_OFF);

    prep_kernel<<<dim3(256, 6), 256, 0, stream>>>(x, wf, bf, wg, bg, wh, bh, wv,
                                                  fxB, wvB, frag);
    attn_kernel<<<1024, 512, 0, stream>>>(x, fxB, frag, wvB, bv, gamma, out);
}

// Round 27
// 38.876 us; speedup vs baseline: 1.1684x; 1.0076x over previous
//
#include <hip/hip_runtime.h>
#include <hip/hip_bf16.h>
#include <math.h>

#define BB 16
#define CC 64
#define HW 4096
#define MM 1024
#define CK 8
#define CV 32
#define LOG2E 1.4426950408889634f

typedef float f32x4 __attribute__((ext_vector_type(4)));
typedef short s16x8 __attribute__((ext_vector_type(8)));

union U4 { uint4 u; s16x8 s; };

__device__ inline unsigned short bfu(float a) {           // RNE (prep only)
    __hip_bfloat16 h = __float2bfloat16(a);
    union { __hip_bfloat16 h; unsigned short u; } c; c.h = h; return c.u;
}
__device__ inline unsigned int pk2bf(float a, float b) {  // RNE pack
    return (unsigned int)bfu(a) | ((unsigned int)bfu(b) << 16);
}
// Trunc pack via single v_perm_b32 (byte gather [a2,a3,b2,b3] ==
// (a>>16)|(b&0xffff0000)): 1 VALU op vs 2-3 for shift+and_or. VALU is the
// busiest pipe in attn (R24 A/B), so pack ops are on the critical path.
__device__ inline unsigned int pk2bf_t(float a, float b) {
#if __has_builtin(__builtin_amdgcn_perm)
    return __builtin_amdgcn_perm(__float_as_uint(b), __float_as_uint(a),
                                 0x07060302u);
#else
    return (__float_as_uint(a) >> 16) | (__float_as_uint(b) & 0xffff0000u);
#endif
}

// Hardware exp2 (v_exp_f32, trans pipe). A/B ledger (direct totals):
// hwexp2 42.71 (R23) < mixed trans/VALU 45.42 (R24) < fexp2i 52.4 (R20).
// Keep exp ENTIRELY off the VALU pipe.
__device__ inline float hwexp2(float s) {
#if __has_builtin(__builtin_amdgcn_exp2f)
    return __builtin_amdgcn_exp2f(s);
#else
    float r;
    asm volatile("v_exp_f32 %0, %1\n\ts_nop 1" : "=v"(r) : "v"(s));
    return r;
#endif
}

// Workspace layout (bytes):
//   fxB  bf16 [b][q][8]            @ 0        (1,048,576)
//   wvB  bf16 tiled [4][64][8]     @ 2359296  (4,096)
//   frag bf16 [b][g][4][64][8]     @ 2363392  (2,097,152)
#define FXB_OFF 0
#define WVB_OFF 2359296
#define FRG_OFF 2363392

// ---------------------------------------------------------------------------
// Kernel A: conv f/g/h split by OUTPUT channels (blockIdx.y = chunk:
// 0=f, 1=g, 2..5=h quarters). Pool via shfl_xor(1,2). Writes frag operand
// tiles DIRECTLY (no tile_kernel).
// ---------------------------------------------------------------------------
__global__ __launch_bounds__(256, 6) void prep_kernel(
    const float* __restrict__ x,
    const float* __restrict__ wf, const float* __restrict__ bf,
    const float* __restrict__ wg, const float* __restrict__ bg,
    const float* __restrict__ wh, const float* __restrict__ bh,
    const float* __restrict__ wv,
    unsigned short* __restrict__ fxB, unsigned short* __restrict__ wvB,
    unsigned short* __restrict__ frag)
{
    __shared__ __align__(16) float wsm[8 * CC];
    __shared__ __align__(16) unsigned short sHp[64][8];

    int tid   = threadIdx.x;
    int chunk = blockIdx.y;            // 0=f 1=g 2..5=h
    const float* wsrc = (chunk == 0) ? wf : (chunk == 1) ? wg : (wh + (size_t)(chunk - 2) * 8 * CC);
    const float* bsrc = (chunk == 0) ? bf : (chunk == 1) ? bg : (bh + (chunk - 2) * 8);

    for (int i = tid; i < 8 * CC; i += 256) wsm[i] = wsrc[i];

    if (blockIdx.x == 0 && chunk == 0) {
        int t = tid >> 6, ll = tid & 63;
        const float* wr = wv + (size_t)(t * 16 + (ll & 15)) * CV + ((ll >> 4) * 8);
        uint4 wu;
        wu.x = pk2bf(wr[0], wr[1]); wu.y = pk2bf(wr[2], wr[3]);
        wu.z = pk2bf(wr[4], wr[5]); wu.w = pk2bf(wr[6], wr[7]);
        *(uint4*)(wvB + (size_t)tid * 8) = wu;
    }
    __syncthreads();

    int wave = tid >> 6, l = tid & 63;
    int wp = blockIdx.x * 4 + wave;    // wave-position 0..1023
    int b  = wp >> 6;                  // batch (same for whole block: 4|64)
    int t2 = wp & 63;
    int rpair = t2 >> 1, chalf = t2 & 1;
    int col = chalf * 32 + (l >> 2) * 2 + (l & 1);
    int row = rpair * 2 + ((l >> 1) & 1);
    int pix = row * 64 + col;

    float o8[8];
#pragma unroll
    for (int o = 0; o < 8; ++o) o8[o] = bsrc[o];

    const float* xp = x + (size_t)b * CC * HW + pix;
#pragma unroll 4
    for (int c4 = 0; c4 < CC; c4 += 4) {
        float v0 = xp[(c4 + 0) * HW];
        float v1 = xp[(c4 + 1) * HW];
        float v2 = xp[(c4 + 2) * HW];
        float v3 = xp[(c4 + 3) * HW];
#pragma unroll
        for (int o = 0; o < 8; ++o) {
            float4 w = *(const float4*)&wsm[o * CC + c4];
            o8[o] = fmaf(w.x, v0, fmaf(w.y, v1, fmaf(w.z, v2, fmaf(w.w, v3, o8[o]))));
        }
    }

    if (chunk == 0) {
        uint4 fu;
        fu.x = pk2bf(o8[0] * LOG2E, o8[1] * LOG2E);
        fu.y = pk2bf(o8[2] * LOG2E, o8[3] * LOG2E);
        fu.z = pk2bf(o8[4] * LOG2E, o8[5] * LOG2E);
        fu.w = pk2bf(o8[6] * LOG2E, o8[7] * LOG2E);
        *(uint4*)(fxB + (size_t)(b * HW + pix) * CK) = fu;
    } else {
#pragma unroll
        for (int o = 0; o < 8; ++o) {
            o8[o] = fmaxf(o8[o], __shfl_xor(o8[o], 1, 64));
            o8[o] = fmaxf(o8[o], __shfl_xor(o8[o], 2, 64));
        }
        int ppl = l >> 2;
        if (chunk == 1) {
            if ((l & 3) == 0) {
                uint4 gu;
                gu.x = pk2bf(o8[0], o8[1]); gu.y = pk2bf(o8[2], o8[3]);
                gu.z = pk2bf(o8[4], o8[5]); gu.w = pk2bf(o8[6], o8[7]);
                int pp = rpair * 32 + chalf * 16 + ppl;
                int r  = pp & 31, g = pp >> 5;
                int q16d  = (r & 3) | ((r >> 1) & 12);
                int which = (r >> 2) & 1;
                size_t base = (size_t)((b * 32 + g) * 4 + which) * 64 * 8;
#pragma unroll
                for (int hh = 0; hh < 4; ++hh)
                    *(uint4*)(frag + base + (size_t)(hh * 16 + q16d) * 8) = gu;
            }
        } else {
            if ((l & 3) == 0) {
                uint4 hu;
                hu.x = pk2bf(o8[0], o8[1]); hu.y = pk2bf(o8[2], o8[3]);
                hu.z = pk2bf(o8[4], o8[5]); hu.w = pk2bf(o8[6], o8[7]);
                *(uint4*)&sHp[wave * 16 + ppl][0] = hu;
            }
            __syncthreads();
            if (tid < 64) {
                int cl = tid & 7, gg = (tid >> 3) & 1, hh = tid >> 4;
                int c  = (chunk - 2) * 8 + cl;
                int which = ((c >> 2) & 1) ? 3 : 2;
                int prm   = (which == 3) ? (c - 4) : c;
                int q16d  = (prm & 3) | ((prm >> 1) & 12);
                int ppb   = (blockIdx.x * 4 & 63) * 16;
                int g     = (ppb >> 5) + gg;
                int px    = gg * 32 + hh * 8;
                uint4 hv;
                hv.x = (unsigned)sHp[px + 0][cl] | ((unsigned)sHp[px + 1][cl] << 16);
                hv.y = (unsigned)sHp[px + 2][cl] | ((unsigned)sHp[px + 3][cl] << 16);
                hv.z = (unsigned)sHp[px + 4][cl] | ((unsigned)sHp[px + 5][cl] << 16);
                hv.w = (unsigned)sHp[px + 6][cl] | ((unsigned)sHp[px + 7][cl] << 16);
                *(uint4*)(frag + ((size_t)((b * 32 + g) * 4 + which) * 64
                                  + hh * 16 + q16d) * 8) = hv;
            }
        }
    }
}

// ---------------------------------------------------------------------------
// Kernel B: MFMA flash attention. Block = 64 queries, 512 thr (8 waves).
// R27 = R26 (best: 39.17us) with pk2bf_t lowered to a single v_perm_b32
// (was 2-3 VALU ops). T=4 Q-tiles per wave over its key-eighth; pure
// hwexp2; s_setprio(1/0) around the MFMA+exp cluster (T5, +1.6% measured);
// (512,4) = 128-VGPR cap.
// ---------------------------------------------------------------------------
__global__ __launch_bounds__(512, 4) void attn_kernel(
    const float* __restrict__ x,
    const unsigned short* __restrict__ fxB, const unsigned short* __restrict__ frag,
    const unsigned short* __restrict__ wvB,
    const float* __restrict__ bv, const float* __restrict__ gamma,
    float* __restrict__ out)
{
    __shared__ float sAcc[4][8][8][64];   // [qt][kq][elem][lane] 64KB
    __shared__ float sSum[4][8][64];      // 8KB

    int tid = threadIdx.x;
    int l   = tid & 63;
    int w   = tid >> 6;                        // 0..7 = key eighth
    int b   = blockIdx.x >> 6;                 // 64 blocks per batch
    int qb  = (blockIdx.x & 63) * 64;
    int q16 = l & 15;
    int h   = l >> 4;
    bool lo16 = (l < 16);

    U4 qf[4];
#pragma unroll
    for (int t = 0; t < 4; ++t) {
        uint4 v = *(const uint4*)(fxB + (size_t)(b * HW + qb + t * 16 + q16) * CK);
        if (!lo16) { v.x = 0; v.y = 0; v.z = 0; v.w = 0; }
        qf[t].u = v;
    }

    f32x4 zz = {0.f, 0.f, 0.f, 0.f};
    f32x4 acc[4][2];
#pragma unroll
    for (int t = 0; t < 4; ++t) { acc[t][0] = zz; acc[t][1] = zz; }
    float ssum[4] = {0.f, 0.f, 0.f, 0.f};

    const unsigned short* fb = frag + ((size_t)(b * 32 + w * 4) * 4) * 64 * 8
                                    + (size_t)l * 8;

#pragma unroll 2
    for (int gi = 0; gi < 4; ++gi) {
        U4 ga, gb2, v0, v1;
        ga.u  = *(const uint4*)(fb + 0 * 512);
        gb2.u = *(const uint4*)(fb + 1 * 512);
        v0.u  = *(const uint4*)(fb + 2 * 512);
        v1.u  = *(const uint4*)(fb + 3 * 512);
        fb += 2048;

        __builtin_amdgcn_s_setprio(1);
#pragma unroll
        for (int t = 0; t < 4; ++t) {
            f32x4 s0 = __builtin_amdgcn_mfma_f32_16x16x32_bf16(ga.s,  qf[t].s, zz, 0, 0, 0);
            f32x4 s1 = __builtin_amdgcn_mfma_f32_16x16x32_bf16(gb2.s, qf[t].s, zz, 0, 0, 0);
            float e0 = hwexp2(s0.x), e1 = hwexp2(s0.y), e2 = hwexp2(s0.z), e3 = hwexp2(s0.w);
            float e4 = hwexp2(s1.x), e5 = hwexp2(s1.y), e6 = hwexp2(s1.z), e7 = hwexp2(s1.w);
            ssum[t] += ((e0 + e1) + (e2 + e3)) + ((e4 + e5) + (e6 + e7));
            U4 bp;
            bp.u.x = pk2bf_t(e0, e1); bp.u.y = pk2bf_t(e2, e3);
            bp.u.z = pk2bf_t(e4, e5); bp.u.w = pk2bf_t(e6, e7);
            acc[t][0] = __builtin_amdgcn_mfma_f32_16x16x32_bf16(v0.s, bp.s, acc[t][0], 0, 0, 0);
            acc[t][1] = __builtin_amdgcn_mfma_f32_16x16x32_bf16(v1.s, bp.s, acc[t][1], 0, 0, 0);
        }
        __builtin_amdgcn_s_setprio(0);
    }

#pragma unroll
    for (int t = 0; t < 4; ++t) {
#pragma unroll
        for (int e = 0; e < 4; ++e) {
            sAcc[t][w][e][l]     = acc[t][0][e];
            sAcc[t][w][4 + e][l] = acc[t][1][e];
        }
        sSum[t][w][l] = ssum[t];
    }
    __syncthreads();

    int qt_f = w >> 1;
    int oth  = w & 1;
    f32x4 ca0 = zz, ca1 = zz;
    float cs = 0.f;
#pragma unroll
    for (int k2 = 0; k2 < 8; ++k2) {
#pragma unroll
        for (int e = 0; e < 4; ++e) {
            ca0[e] += sAcc[qt_f][k2][e][l];
            ca1[e] += sAcc[qt_f][k2][4 + e][l];
        }
        cs += sSum[qt_f][k2][l];
    }
    cs += __shfl_xor(cs, 16, 64);
    cs += __shfl_xor(cs, 32, 64);
    float inv = 1.0f / cs;

    U4 mb;
    mb.u.x = pk2bf_t(ca0.x * inv, ca0.y * inv);
    mb.u.y = pk2bf_t(ca0.z * inv, ca0.w * inv);
    mb.u.z = pk2bf_t(ca1.x * inv, ca1.y * inv);
    mb.u.w = pk2bf_t(ca1.z * inv, ca1.w * inv);

    float gm = gamma[0];
    int q = qb + qt_f * 16 + q16;
    const float* xq = x + (size_t)b * CC * HW + q;
    float*       oq = out + (size_t)b * CC * HW + q;
#pragma unroll
    for (int i = 0; i < 2; ++i) {
        int ot = oth * 2 + i;
        U4 wva;
        wva.u = *(const uint4*)(wvB + (size_t)(ot * 64 + l) * CK);
        f32x4 d = __builtin_amdgcn_mfma_f32_16x16x32_bf16(wva.s, mb.s, zz, 0, 0, 0);
#pragma unroll
        for (int r = 0; r < 4; ++r) {
            int o = ot * 16 + h * 4 + r;
            oq[(size_t)o * HW] = xq[(size_t)o * HW] + gm * (d[r] + bv[o]);
        }
    }
}

extern "C" void kernel_launch(void* const* d_in, const int* in_sizes, int n_in,
                              void* d_out, int out_size, void* d_ws, size_t ws_size,
                              hipStream_t stream) {
    const float* x     = (const float*)d_in[0];
    const float* wf    = (const float*)d_in[1];
    const float* bf    = (const float*)d_in[2];
    const float* wg    = (const float*)d_in[3];
    const float* bg    = (const float*)d_in[4];
    const float* wh    = (const float*)d_in[5];
    const float* bh    = (const float*)d_in[6];
    const float* wv    = (const float*)d_in[7];
    const float* bv    = (const float*)d_in[8];
    const float* gamma = (const float*)d_in[9];
    float* out = (float*)d_out;
    char* ws = (char*)d_ws;

    unsigned short* fxB  = (unsigned short*)(ws + FXB_OFF);
    unsigned short* wvB  = (unsigned short*)(ws + WVB_OFF);
    unsigned short* frag = (unsigned short*)(ws + FRG_OFF);

    prep_kernel<<<dim3(256, 6), 256, 0, stream>>>(x, wf, bf, wg, bg, wh, bh, wv,
                                                  fxB, wvB, frag);
    attn_kernel<<<1024, 512, 0, stream>>>(x, fxB, frag, wvB, bv, gamma, out);
}

// Round 28
// 38.478 us; speedup vs baseline: 1.1805x; 1.0103x over previous
//
#include <hip/hip_runtime.h>
#include <hip/hip_bf16.h>
#include <math.h>

#define BB 16
#define CC 64
#define HW 4096
#define MM 1024
#define CK 8
#define CV 32
#define LOG2E 1.4426950408889634f

typedef float f32x4 __attribute__((ext_vector_type(4)));
typedef short s16x8 __attribute__((ext_vector_type(8)));

union U4 { uint4 u; s16x8 s; };

__device__ inline unsigned short bfu(float a) {           // RNE (prep only)
    __hip_bfloat16 h = __float2bfloat16(a);
    union { __hip_bfloat16 h; unsigned short u; } c; c.h = h; return c.u;
}
__device__ inline unsigned int pk2bf(float a, float b) {  // RNE pack
    return (unsigned int)bfu(a) | ((unsigned int)bfu(b) << 16);
}
// Trunc pack via single v_perm_b32 (A/B-verified win: R26 39.17 -> R27 38.88).
__device__ inline unsigned int pk2bf_t(float a, float b) {
#if __has_builtin(__builtin_amdgcn_perm)
    return __builtin_amdgcn_perm(__float_as_uint(b), __float_as_uint(a),
                                 0x07060302u);
#else
    return (__float_as_uint(a) >> 16) | (__float_as_uint(b) & 0xffff0000u);
#endif
}

// Hardware exp2 (v_exp_f32, trans pipe). A/B ledger (direct totals):
// hwexp2 42.71 (R23) < mixed trans/VALU 45.42 (R24) < fexp2i 52.4 (R20).
__device__ inline float hwexp2(float s) {
#if __has_builtin(__builtin_amdgcn_exp2f)
    return __builtin_amdgcn_exp2f(s);
#else
    float r;
    asm volatile("v_exp_f32 %0, %1\n\ts_nop 1" : "=v"(r) : "v"(s));
    return r;
#endif
}

// Workspace layout (bytes):
//   fxB  bf16 [b][q][8]            @ 0        (1,048,576)
//   wvB  bf16 tiled [4][64][8]     @ 2359296  (4,096)
//   frag bf16 [b][g][4][64][8]     @ 2363392  (2,097,152)
#define FXB_OFF 0
#define WVB_OFF 2359296
#define FRG_OFF 2363392

// ---------------------------------------------------------------------------
// Kernel A: conv f/g/h split by OUTPUT channels (blockIdx.y = chunk:
// 0=f, 1=g, 2..5=h quarters). Pool via shfl_xor(1,2). Writes frag operand
// tiles DIRECTLY (no tile_kernel).
// ---------------------------------------------------------------------------
__global__ __launch_bounds__(256, 6) void prep_kernel(
    const float* __restrict__ x,
    const float* __restrict__ wf, const float* __restrict__ bf,
    const float* __restrict__ wg, const float* __restrict__ bg,
    const float* __restrict__ wh, const float* __restrict__ bh,
    const float* __restrict__ wv,
    unsigned short* __restrict__ fxB, unsigned short* __restrict__ wvB,
    unsigned short* __restrict__ frag)
{
    __shared__ __align__(16) float wsm[8 * CC];
    __shared__ __align__(16) unsigned short sHp[64][8];

    int tid   = threadIdx.x;
    int chunk = blockIdx.y;            // 0=f 1=g 2..5=h
    const float* wsrc = (chunk == 0) ? wf : (chunk == 1) ? wg : (wh + (size_t)(chunk - 2) * 8 * CC);
    const float* bsrc = (chunk == 0) ? bf : (chunk == 1) ? bg : (bh + (chunk - 2) * 8);

    for (int i = tid; i < 8 * CC; i += 256) wsm[i] = wsrc[i];

    if (blockIdx.x == 0 && chunk == 0) {
        int t = tid >> 6, ll = tid & 63;
        const float* wr = wv + (size_t)(t * 16 + (ll & 15)) * CV + ((ll >> 4) * 8);
        uint4 wu;
        wu.x = pk2bf(wr[0], wr[1]); wu.y = pk2bf(wr[2], wr[3]);
        wu.z = pk2bf(wr[4], wr[5]); wu.w = pk2bf(wr[6], wr[7]);
        *(uint4*)(wvB + (size_t)tid * 8) = wu;
    }
    __syncthreads();

    int wave = tid >> 6, l = tid & 63;
    int wp = blockIdx.x * 4 + wave;    // wave-position 0..1023
    int b  = wp >> 6;                  // batch (same for whole block: 4|64)
    int t2 = wp & 63;
    int rpair = t2 >> 1, chalf = t2 & 1;
    int col = chalf * 32 + (l >> 2) * 2 + (l & 1);
    int row = rpair * 2 + ((l >> 1) & 1);
    int pix = row * 64 + col;

    float o8[8];
#pragma unroll
    for (int o = 0; o < 8; ++o) o8[o] = bsrc[o];

    const float* xp = x + (size_t)b * CC * HW + pix;
#pragma unroll 4
    for (int c4 = 0; c4 < CC; c4 += 4) {
        float v0 = xp[(c4 + 0) * HW];
        float v1 = xp[(c4 + 1) * HW];
        float v2 = xp[(c4 + 2) * HW];
        float v3 = xp[(c4 + 3) * HW];
#pragma unroll
        for (int o = 0; o < 8; ++o) {
            float4 w = *(const float4*)&wsm[o * CC + c4];
            o8[o] = fmaf(w.x, v0, fmaf(w.y, v1, fmaf(w.z, v2, fmaf(w.w, v3, o8[o]))));
        }
    }

    if (chunk == 0) {
        uint4 fu;
        fu.x = pk2bf(o8[0] * LOG2E, o8[1] * LOG2E);
        fu.y = pk2bf(o8[2] * LOG2E, o8[3] * LOG2E);
        fu.z = pk2bf(o8[4] * LOG2E, o8[5] * LOG2E);
        fu.w = pk2bf(o8[6] * LOG2E, o8[7] * LOG2E);
        *(uint4*)(fxB + (size_t)(b * HW + pix) * CK) = fu;
    } else {
#pragma unroll
        for (int o = 0; o < 8; ++o) {
            o8[o] = fmaxf(o8[o], __shfl_xor(o8[o], 1, 64));
            o8[o] = fmaxf(o8[o], __shfl_xor(o8[o], 2, 64));
        }
        int ppl = l >> 2;
        if (chunk == 1) {
            if ((l & 3) == 0) {
                uint4 gu;
                gu.x = pk2bf(o8[0], o8[1]); gu.y = pk2bf(o8[2], o8[3]);
                gu.z = pk2bf(o8[4], o8[5]); gu.w = pk2bf(o8[6], o8[7]);
                int pp = rpair * 32 + chalf * 16 + ppl;
                int r  = pp & 31, g = pp >> 5;
                int q16d  = (r & 3) | ((r >> 1) & 12);
                int which = (r >> 2) & 1;
                size_t base = (size_t)((b * 32 + g) * 4 + which) * 64 * 8;
#pragma unroll
                for (int hh = 0; hh < 4; ++hh)
                    *(uint4*)(frag + base + (size_t)(hh * 16 + q16d) * 8) = gu;
            }
        } else {
            if ((l & 3) == 0) {
                uint4 hu;
                hu.x = pk2bf(o8[0], o8[1]); hu.y = pk2bf(o8[2], o8[3]);
                hu.z = pk2bf(o8[4], o8[5]); hu.w = pk2bf(o8[6], o8[7]);
                *(uint4*)&sHp[wave * 16 + ppl][0] = hu;
            }
            __syncthreads();
            if (tid < 64) {
                int cl = tid & 7, gg = (tid >> 3) & 1, hh = tid >> 4;
                int c  = (chunk - 2) * 8 + cl;
                int which = ((c >> 2) & 1) ? 3 : 2;
                int prm   = (which == 3) ? (c - 4) : c;
                int q16d  = (prm & 3) | ((prm >> 1) & 12);
                int ppb   = (blockIdx.x * 4 & 63) * 16;
                int g     = (ppb >> 5) + gg;
                int px    = gg * 32 + hh * 8;
                uint4 hv;
                hv.x = (unsigned)sHp[px + 0][cl] | ((unsigned)sHp[px + 1][cl] << 16);
                hv.y = (unsigned)sHp[px + 2][cl] | ((unsigned)sHp[px + 3][cl] << 16);
                hv.z = (unsigned)sHp[px + 4][cl] | ((unsigned)sHp[px + 5][cl] << 16);
                hv.w = (unsigned)sHp[px + 6][cl] | ((unsigned)sHp[px + 7][cl] << 16);
                *(uint4*)(frag + ((size_t)((b * 32 + g) * 4 + which) * 64
                                  + hh * 16 + q16d) * 8) = hv;
            }
        }
    }
}

// ---------------------------------------------------------------------------
// Kernel B: MFMA flash attention. Block = 64 queries, 512 thr (8 waves).
// R28 = R27 (best: 38.88us) with the group loop FULLY unrolled (was
// unroll 2): all 16 (g,t) chains visible to the scheduler at once, fb
// pointer bumps become compile-time offsets. Spill check: WRITE_SIZE must
// stay ~17MB (R8/R12 spill signature: 80-137MB -> revert).
// T=4 Q-tiles per wave over its key-eighth; pure hwexp2; s_setprio around
// the MFMA+exp cluster; v_perm pack; (512,4) = 128-VGPR cap.
// ---------------------------------------------------------------------------
__global__ __launch_bounds__(512, 4) void attn_kernel(
    const float* __restrict__ x,
    const unsigned short* __restrict__ fxB, const unsigned short* __restrict__ frag,
    const unsigned short* __restrict__ wvB,
    const float* __restrict__ bv, const float* __restrict__ gamma,
    float* __restrict__ out)
{
    __shared__ float sAcc[4][8][8][64];   // [qt][kq][elem][lane] 64KB
    __shared__ float sSum[4][8][64];      // 8KB

    int tid = threadIdx.x;
    int l   = tid & 63;
    int w   = tid >> 6;                        // 0..7 = key eighth
    int b   = blockIdx.x >> 6;                 // 64 blocks per batch
    int qb  = (blockIdx.x & 63) * 64;
    int q16 = l & 15;
    int h   = l >> 4;
    bool lo16 = (l < 16);

    U4 qf[4];
#pragma unroll
    for (int t = 0; t < 4; ++t) {
        uint4 v = *(const uint4*)(fxB + (size_t)(b * HW + qb + t * 16 + q16) * CK);
        if (!lo16) { v.x = 0; v.y = 0; v.z = 0; v.w = 0; }
        qf[t].u = v;
    }

    f32x4 zz = {0.f, 0.f, 0.f, 0.f};
    f32x4 acc[4][2];
#pragma unroll
    for (int t = 0; t < 4; ++t) { acc[t][0] = zz; acc[t][1] = zz; }
    float ssum[4] = {0.f, 0.f, 0.f, 0.f};

    const unsigned short* fb = frag + ((size_t)(b * 32 + w * 4) * 4) * 64 * 8
                                    + (size_t)l * 8;

#pragma unroll
    for (int gi = 0; gi < 4; ++gi) {
        U4 ga, gb2, v0, v1;
        const unsigned short* fg = fb + (size_t)gi * 2048;
        ga.u  = *(const uint4*)(fg + 0 * 512);
        gb2.u = *(const uint4*)(fg + 1 * 512);
        v0.u  = *(const uint4*)(fg + 2 * 512);
        v1.u  = *(const uint4*)(fg + 3 * 512);

        __builtin_amdgcn_s_setprio(1);
#pragma unroll
        for (int t = 0; t < 4; ++t) {
            f32x4 s0 = __builtin_amdgcn_mfma_f32_16x16x32_bf16(ga.s,  qf[t].s, zz, 0, 0, 0);
            f32x4 s1 = __builtin_amdgcn_mfma_f32_16x16x32_bf16(gb2.s, qf[t].s, zz, 0, 0, 0);
            float e0 = hwexp2(s0.x), e1 = hwexp2(s0.y), e2 = hwexp2(s0.z), e3 = hwexp2(s0.w);
            float e4 = hwexp2(s1.x), e5 = hwexp2(s1.y), e6 = hwexp2(s1.z), e7 = hwexp2(s1.w);
            ssum[t] += ((e0 + e1) + (e2 + e3)) + ((e4 + e5) + (e6 + e7));
            U4 bp;
            bp.u.x = pk2bf_t(e0, e1); bp.u.y = pk2bf_t(e2, e3);
            bp.u.z = pk2bf_t(e4, e5); bp.u.w = pk2bf_t(e6, e7);
            acc[t][0] = __builtin_amdgcn_mfma_f32_16x16x32_bf16(v0.s, bp.s, acc[t][0], 0, 0, 0);
            acc[t][1] = __builtin_amdgcn_mfma_f32_16x16x32_bf16(v1.s, bp.s, acc[t][1], 0, 0, 0);
        }
        __builtin_amdgcn_s_setprio(0);
    }

#pragma unroll
    for (int t = 0; t < 4; ++t) {
#pragma unroll
        for (int e = 0; e < 4; ++e) {
            sAcc[t][w][e][l]     = acc[t][0][e];
            sAcc[t][w][4 + e][l] = acc[t][1][e];
        }
        sSum[t][w][l] = ssum[t];
    }
    __syncthreads();

    int qt_f = w >> 1;
    int oth  = w & 1;
    f32x4 ca0 = zz, ca1 = zz;
    float cs = 0.f;
#pragma unroll
    for (int k2 = 0; k2 < 8; ++k2) {
#pragma unroll
        for (int e = 0; e < 4; ++e) {
            ca0[e] += sAcc[qt_f][k2][e][l];
            ca1[e] += sAcc[qt_f][k2][4 + e][l];
        }
        cs += sSum[qt_f][k2][l];
    }
    cs += __shfl_xor(cs, 16, 64);
    cs += __shfl_xor(cs, 32, 64);
    float inv = 1.0f / cs;

    U4 mb;
    mb.u.x = pk2bf_t(ca0.x * inv, ca0.y * inv);
    mb.u.y = pk2bf_t(ca0.z * inv, ca0.w * inv);
    mb.u.z = pk2bf_t(ca1.x * inv, ca1.y * inv);
    mb.u.w = pk2bf_t(ca1.z * inv, ca1.w * inv);

    float gm = gamma[0];
    int q = qb + qt_f * 16 + q16;
    const float* xq = x + (size_t)b * CC * HW + q;
    float*       oq = out + (size_t)b * CC * HW + q;
#pragma unroll
    for (int i = 0; i < 2; ++i) {
        int ot = oth * 2 + i;
        U4 wva;
        wva.u = *(const uint4*)(wvB + (size_t)(ot * 64 + l) * CK);
        f32x4 d = __builtin_amdgcn_mfma_f32_16x16x32_bf16(wva.s, mb.s, zz, 0, 0, 0);
#pragma unroll
        for (int r = 0; r < 4; ++r) {
            int o = ot * 16 + h * 4 + r;
            oq[(size_t)o * HW] = xq[(size_t)o * HW] + gm * (d[r] + bv[o]);
        }
    }
}

extern "C" void kernel_launch(void* const* d_in, const int* in_sizes, int n_in,
                              void* d_out, int out_size, void* d_ws, size_t ws_size,
                              hipStream_t stream) {
    const float* x     = (const float*)d_in[0];
    const float* wf    = (const float*)d_in[1];
    const float* bf    = (const float*)d_in[2];
    const float* wg    = (const float*)d_in[3];
    const float* bg    = (const float*)d_in[4];
    const float* wh    = (const float*)d_in[5];
    const float* bh    = (const float*)d_in[6];
    const float* wv    = (const float*)d_in[7];
    const float* bv    = (const float*)d_in[8];
    const float* gamma = (const float*)d_in[9];
    float* out = (float*)d_out;
    char* ws = (char*)d_ws;

    unsigned short* fxB  = (unsigned short*)(ws + FXB_OFF);
    unsigned short* wvB  = (unsigned short*)(ws + WVB_OFF);
    unsigned short* frag = (unsigned short*)(ws + FRG_OFF);

    prep_kernel<<<dim3(256, 6), 256, 0, stream>>>(x, wf, bf, wg, bg, wh, bh, wv,
                                                  fxB, wvB, frag);
    attn_kernel<<<1024, 512, 0, stream>>>(x, fxB, frag, wvB, bv, gamma, out);
}

// Round 29
// 38.413 us; speedup vs baseline: 1.1825x; 1.0017x over previous
//
#include <hip/hip_runtime.h>
#include <hip/hip_bf16.h>
#include <math.h>

#define BB 16
#define CC 64
#define HW 4096
#define MM 1024
#define CK 8
#define CV 32
#define LOG2E 1.4426950408889634f

typedef float f32x4 __attribute__((ext_vector_type(4)));
typedef short s16x8 __attribute__((ext_vector_type(8)));

union U4 { uint4 u; s16x8 s; };

__device__ inline unsigned short bfu(float a) {           // RNE (prep only)
    __hip_bfloat16 h = __float2bfloat16(a);
    union { __hip_bfloat16 h; unsigned short u; } c; c.h = h; return c.u;
}
__device__ inline unsigned int pk2bf(float a, float b) {  // RNE pack
    return (unsigned int)bfu(a) | ((unsigned int)bfu(b) << 16);
}
// Trunc pack via single v_perm_b32 (A/B-verified win: R26 39.17 -> R27 38.88).
__device__ inline unsigned int pk2bf_t(float a, float b) {
#if __has_builtin(__builtin_amdgcn_perm)
    return __builtin_amdgcn_perm(__float_as_uint(b), __float_as_uint(a),
                                 0x07060302u);
#else
    return (__float_as_uint(a) >> 16) | (__float_as_uint(b) & 0xffff0000u);
#endif
}

// Hardware exp2 (v_exp_f32, trans pipe). A/B ledger (direct totals):
// hwexp2 42.71 (R23) < mixed trans/VALU 45.42 (R24) < fexp2i 52.4 (R20).
__device__ inline float hwexp2(float s) {
#if __has_builtin(__builtin_amdgcn_exp2f)
    return __builtin_amdgcn_exp2f(s);
#else
    float r;
    asm volatile("v_exp_f32 %0, %1\n\ts_nop 1" : "=v"(r) : "v"(s));
    return r;
#endif
}

// Workspace layout (bytes):
//   fxB  bf16 [b][q][8]            @ 0        (1,048,576)
//   wvB  bf16 tiled [4][64][8]     @ 2359296  (4,096)
//   frag bf16 [b][g][4][64][8]     @ 2363392  (2,097,152)
#define FXB_OFF 0
#define WVB_OFF 2359296
#define FRG_OFF 2363392

// ---------------------------------------------------------------------------
// Kernel A: conv f/g/h split by OUTPUT channels (blockIdx.y = chunk:
// 0=f, 1=g, 2..5=h quarters). Pool via shfl_xor(1,2). Writes frag operand
// tiles DIRECTLY (no tile_kernel).
// ---------------------------------------------------------------------------
__global__ __launch_bounds__(256, 6) void prep_kernel(
    const float* __restrict__ x,
    const float* __restrict__ wf, const float* __restrict__ bf,
    const float* __restrict__ wg, const float* __restrict__ bg,
    const float* __restrict__ wh, const float* __restrict__ bh,
    const float* __restrict__ wv,
    unsigned short* __restrict__ fxB, unsigned short* __restrict__ wvB,
    unsigned short* __restrict__ frag)
{
    __shared__ __align__(16) float wsm[8 * CC];
    __shared__ __align__(16) unsigned short sHp[64][8];

    int tid   = threadIdx.x;
    int chunk = blockIdx.y;            // 0=f 1=g 2..5=h
    const float* wsrc = (chunk == 0) ? wf : (chunk == 1) ? wg : (wh + (size_t)(chunk - 2) * 8 * CC);
    const float* bsrc = (chunk == 0) ? bf : (chunk == 1) ? bg : (bh + (chunk - 2) * 8);

    for (int i = tid; i < 8 * CC; i += 256) wsm[i] = wsrc[i];

    if (blockIdx.x == 0 && chunk == 0) {
        int t = tid >> 6, ll = tid & 63;
        const float* wr = wv + (size_t)(t * 16 + (ll & 15)) * CV + ((ll >> 4) * 8);
        uint4 wu;
        wu.x = pk2bf(wr[0], wr[1]); wu.y = pk2bf(wr[2], wr[3]);
        wu.z = pk2bf(wr[4], wr[5]); wu.w = pk2bf(wr[6], wr[7]);
        *(uint4*)(wvB + (size_t)tid * 8) = wu;
    }
    __syncthreads();

    int wave = tid >> 6, l = tid & 63;
    int wp = blockIdx.x * 4 + wave;    // wave-position 0..1023
    int b  = wp >> 6;                  // batch (same for whole block: 4|64)
    int t2 = wp & 63;
    int rpair = t2 >> 1, chalf = t2 & 1;
    int col = chalf * 32 + (l >> 2) * 2 + (l & 1);
    int row = rpair * 2 + ((l >> 1) & 1);
    int pix = row * 64 + col;

    float o8[8];
#pragma unroll
    for (int o = 0; o < 8; ++o) o8[o] = bsrc[o];

    const float* xp = x + (size_t)b * CC * HW + pix;
#pragma unroll 4
    for (int c4 = 0; c4 < CC; c4 += 4) {
        float v0 = xp[(c4 + 0) * HW];
        float v1 = xp[(c4 + 1) * HW];
        float v2 = xp[(c4 + 2) * HW];
        float v3 = xp[(c4 + 3) * HW];
#pragma unroll
        for (int o = 0; o < 8; ++o) {
            float4 w = *(const float4*)&wsm[o * CC + c4];
            o8[o] = fmaf(w.x, v0, fmaf(w.y, v1, fmaf(w.z, v2, fmaf(w.w, v3, o8[o]))));
        }
    }

    if (chunk == 0) {
        uint4 fu;
        fu.x = pk2bf(o8[0] * LOG2E, o8[1] * LOG2E);
        fu.y = pk2bf(o8[2] * LOG2E, o8[3] * LOG2E);
        fu.z = pk2bf(o8[4] * LOG2E, o8[5] * LOG2E);
        fu.w = pk2bf(o8[6] * LOG2E, o8[7] * LOG2E);
        *(uint4*)(fxB + (size_t)(b * HW + pix) * CK) = fu;
    } else {
#pragma unroll
        for (int o = 0; o < 8; ++o) {
            o8[o] = fmaxf(o8[o], __shfl_xor(o8[o], 1, 64));
            o8[o] = fmaxf(o8[o], __shfl_xor(o8[o], 2, 64));
        }
        int ppl = l >> 2;
        if (chunk == 1) {
            if ((l & 3) == 0) {
                uint4 gu;
                gu.x = pk2bf(o8[0], o8[1]); gu.y = pk2bf(o8[2], o8[3]);
                gu.z = pk2bf(o8[4], o8[5]); gu.w = pk2bf(o8[6], o8[7]);
                int pp = rpair * 32 + chalf * 16 + ppl;
                int r  = pp & 31, g = pp >> 5;
                int q16d  = (r & 3) | ((r >> 1) & 12);
                int which = (r >> 2) & 1;
                size_t base = (size_t)((b * 32 + g) * 4 + which) * 64 * 8;
#pragma unroll
                for (int hh = 0; hh < 4; ++hh)
                    *(uint4*)(frag + base + (size_t)(hh * 16 + q16d) * 8) = gu;
            }
        } else {
            if ((l & 3) == 0) {
                uint4 hu;
                hu.x = pk2bf(o8[0], o8[1]); hu.y = pk2bf(o8[2], o8[3]);
                hu.z = pk2bf(o8[4], o8[5]); hu.w = pk2bf(o8[6], o8[7]);
                *(uint4*)&sHp[wave * 16 + ppl][0] = hu;
            }
            __syncthreads();
            if (tid < 64) {
                int cl = tid & 7, gg = (tid >> 3) & 1, hh = tid >> 4;
                int c  = (chunk - 2) * 8 + cl;
                int which = ((c >> 2) & 1) ? 3 : 2;
                int prm   = (which == 3) ? (c - 4) : c;
                int q16d  = (prm & 3) | ((prm >> 1) & 12);
                int ppb   = (blockIdx.x * 4 & 63) * 16;
                int g     = (ppb >> 5) + gg;
                int px    = gg * 32 + hh * 8;
                uint4 hv;
                hv.x = (unsigned)sHp[px + 0][cl] | ((unsigned)sHp[px + 1][cl] << 16);
                hv.y = (unsigned)sHp[px + 2][cl] | ((unsigned)sHp[px + 3][cl] << 16);
                hv.z = (unsigned)sHp[px + 4][cl] | ((unsigned)sHp[px + 5][cl] << 16);
                hv.w = (unsigned)sHp[px + 6][cl] | ((unsigned)sHp[px + 7][cl] << 16);
                *(uint4*)(frag + ((size_t)((b * 32 + g) * 4 + which) * 64
                                  + hh * 16 + q16d) * 8) = hv;
            }
        }
    }
}

// ---------------------------------------------------------------------------
// Kernel B: MFMA flash attention. Block = 64 queries, 512 thr (8 waves).
// R29 = R28 (best: 38.48us) with s_setprio HOISTED: one (1) before the
// fully-unrolled group loop, one (0) after -- removes 6 SALU toggles and
// keeps the wave high-priority through the group seams where next-group
// loads issue (T5 mechanism applied to the whole cluster). Epilogue stays
// prio 0. T=4 Q-tiles per wave over its key-eighth; pure hwexp2; v_perm
// pack; (512,4) = 128-VGPR cap.
// ---------------------------------------------------------------------------
__global__ __launch_bounds__(512, 4) void attn_kernel(
    const float* __restrict__ x,
    const unsigned short* __restrict__ fxB, const unsigned short* __restrict__ frag,
    const unsigned short* __restrict__ wvB,
    const float* __restrict__ bv, const float* __restrict__ gamma,
    float* __restrict__ out)
{
    __shared__ float sAcc[4][8][8][64];   // [qt][kq][elem][lane] 64KB
    __shared__ float sSum[4][8][64];      // 8KB

    int tid = threadIdx.x;
    int l   = tid & 63;
    int w   = tid >> 6;                        // 0..7 = key eighth
    int b   = blockIdx.x >> 6;                 // 64 blocks per batch
    int qb  = (blockIdx.x & 63) * 64;
    int q16 = l & 15;
    int h   = l >> 4;
    bool lo16 = (l < 16);

    U4 qf[4];
#pragma unroll
    for (int t = 0; t < 4; ++t) {
        uint4 v = *(const uint4*)(fxB + (size_t)(b * HW + qb + t * 16 + q16) * CK);
        if (!lo16) { v.x = 0; v.y = 0; v.z = 0; v.w = 0; }
        qf[t].u = v;
    }

    f32x4 zz = {0.f, 0.f, 0.f, 0.f};
    f32x4 acc[4][2];
#pragma unroll
    for (int t = 0; t < 4; ++t) { acc[t][0] = zz; acc[t][1] = zz; }
    float ssum[4] = {0.f, 0.f, 0.f, 0.f};

    const unsigned short* fb = frag + ((size_t)(b * 32 + w * 4) * 4) * 64 * 8
                                    + (size_t)l * 8;

    __builtin_amdgcn_s_setprio(1);         // high prio across the whole
                                           // unrolled compute cluster (T5)
#pragma unroll
    for (int gi = 0; gi < 4; ++gi) {
        U4 ga, gb2, v0, v1;
        const unsigned short* fg = fb + (size_t)gi * 2048;
        ga.u  = *(const uint4*)(fg + 0 * 512);
        gb2.u = *(const uint4*)(fg + 1 * 512);
        v0.u  = *(const uint4*)(fg + 2 * 512);
        v1.u  = *(const uint4*)(fg + 3 * 512);

#pragma unroll
        for (int t = 0; t < 4; ++t) {
            f32x4 s0 = __builtin_amdgcn_mfma_f32_16x16x32_bf16(ga.s,  qf[t].s, zz, 0, 0, 0);
            f32x4 s1 = __builtin_amdgcn_mfma_f32_16x16x32_bf16(gb2.s, qf[t].s, zz, 0, 0, 0);
            float e0 = hwexp2(s0.x), e1 = hwexp2(s0.y), e2 = hwexp2(s0.z), e3 = hwexp2(s0.w);
            float e4 = hwexp2(s1.x), e5 = hwexp2(s1.y), e6 = hwexp2(s1.z), e7 = hwexp2(s1.w);
            ssum[t] += ((e0 + e1) + (e2 + e3)) + ((e4 + e5) + (e6 + e7));
            U4 bp;
            bp.u.x = pk2bf_t(e0, e1); bp.u.y = pk2bf_t(e2, e3);
            bp.u.z = pk2bf_t(e4, e5); bp.u.w = pk2bf_t(e6, e7);
            acc[t][0] = __builtin_amdgcn_mfma_f32_16x16x32_bf16(v0.s, bp.s, acc[t][0], 0, 0, 0);
            acc[t][1] = __builtin_amdgcn_mfma_f32_16x16x32_bf16(v1.s, bp.s, acc[t][1], 0, 0, 0);
        }
    }
    __builtin_amdgcn_s_setprio(0);

#pragma unroll
    for (int t = 0; t < 4; ++t) {
#pragma unroll
        for (int e = 0; e < 4; ++e) {
            sAcc[t][w][e][l]     = acc[t][0][e];
            sAcc[t][w][4 + e][l] = acc[t][1][e];
        }
        sSum[t][w][l] = ssum[t];
    }
    __syncthreads();

    int qt_f = w >> 1;
    int oth  = w & 1;
    f32x4 ca0 = zz, ca1 = zz;
    float cs = 0.f;
#pragma unroll
    for (int k2 = 0; k2 < 8; ++k2) {
#pragma unroll
        for (int e = 0; e < 4; ++e) {
            ca0[e] += sAcc[qt_f][k2][e][l];
            ca1[e] += sAcc[qt_f][k2][4 + e][l];
        }
        cs += sSum[qt_f][k2][l];
    }
    cs += __shfl_xor(cs, 16, 64);
    cs += __shfl_xor(cs, 32, 64);
    float inv = 1.0f / cs;

    U4 mb;
    mb.u.x = pk2bf_t(ca0.x * inv, ca0.y * inv);
    mb.u.y = pk2bf_t(ca0.z * inv, ca0.w * inv);
    mb.u.z = pk2bf_t(ca1.x * inv, ca1.y * inv);
    mb.u.w = pk2bf_t(ca1.z * inv, ca1.w * inv);

    float gm = gamma[0];
    int q = qb + qt_f * 16 + q16;
    const float* xq = x + (size_t)b * CC * HW + q;
    float*       oq = out + (size_t)b * CC * HW + q;
#pragma unroll
    for (int i = 0; i < 2; ++i) {
        int ot = oth * 2 + i;
        U4 wva;
        wva.u = *(const uint4*)(wvB + (size_t)(ot * 64 + l) * CK);
        f32x4 d = __builtin_amdgcn_mfma_f32_16x16x32_bf16(wva.s, mb.s, zz, 0, 0, 0);
#pragma unroll
        for (int r = 0; r < 4; ++r) {
            int o = ot * 16 + h * 4 + r;
            oq[(size_t)o * HW] = xq[(size_t)o * HW] + gm * (d[r] + bv[o]);
        }
    }
}

extern "C" void kernel_launch(void* const* d_in, const int* in_sizes, int n_in,
                              void* d_out, int out_size, void* d_ws, size_t ws_size,
                              hipStream_t stream) {
    const float* x     = (const float*)d_in[0];
    const float* wf    = (const float*)d_in[1];
    const float* bf    = (const float*)d_in[2];
    const float* wg    = (const float*)d_in[3];
    const float* bg    = (const float*)d_in[4];
    const float* wh    = (const float*)d_in[5];
    const float* bh    = (const float*)d_in[6];
    const float* wv    = (const float*)d_in[7];
    const float* bv    = (const float*)d_in[8];
    const float* gamma = (const float*)d_in[9];
    float* out = (float*)d_out;
    char* ws = (char*)d_ws;

    unsigned short* fxB  = (unsigned short*)(ws + FXB_OFF);
    unsigned short* wvB  = (unsigned short*)(ws + WVB_OFF);
    unsigned short* frag = (unsigned short*)(ws + FRG_OFF);

    prep_kernel<<<dim3(256, 6), 256, 0, stream>>>(x, wf, bf, wg, bg, wh, bh, wv,
                                                  fxB, wvB, frag);
    attn_kernel<<<1024, 512, 0, stream>>>(x, fxB, frag, wvB, bv, gamma, out);
}